// Round 4
// baseline (28.500 us; speedup 1.0000x reference)
//
#include <hip/hip_runtime.h>
#include <hip/hip_bf16.h>
#include <math.h>

// Problem constants (match reference: B=4096, H=256, E=256, K=100)
#define BB 4096
#define HH 256
#define EE 256
#define KK 100
#define MAXT 5     // s-tile blocks per head (loop handles nk > 16*MAXT)
#define NHB 16     // histogram blocks (256 samples each)

typedef __bf16 bf16x8 __attribute__((ext_vector_type(8)));
typedef float  f32x4  __attribute__((ext_vector_type(4)));

__device__ __forceinline__ float gelu_exact(float x) {
    return 0.5f * x * (1.0f + erff(x * 0.70710678118654752f));
}

__device__ __forceinline__ float norm_clip(float v, float m, float sd) {
    float z = (v - m) / fmaxf(sd, 1e-8f);
    return fminf(5.0f, fmaxf(-5.0f, z));
}

// Kernel A: blocks 0..255 -> hidden = gelu(z*w1+b1) in bf16 (16 samples each);
// blocks 256..271 -> private 100-bin histogram of 256 samples (LDS, no global
// atomics, no pre-zeroed global memory).
__global__ __launch_bounds__(256) void hidden_hist_kernel(
    const float* __restrict__ values, const float* __restrict__ means,
    const float* __restrict__ stds, const int* __restrict__ head_idx,
    const float* __restrict__ w1, const float* __restrict__ b1,
    __bf16* __restrict__ hidden, int* __restrict__ hist)
{
    const int tid = threadIdx.x;

    if (blockIdx.x < BB / 16) {
        const int s  = blockIdx.x * 16 + (tid >> 4);
        const int h0 = (tid & 15) * 16;
        const float z = norm_clip(values[s], means[s], stds[s]);
        alignas(16) __bf16 g[16];
#pragma unroll
        for (int i = 0; i < 16; i += 4) {
            const float4 wv = *reinterpret_cast<const float4*>(w1 + h0 + i);
            const float4 bv = *reinterpret_cast<const float4*>(b1 + h0 + i);
            g[i + 0] = (__bf16)gelu_exact(fmaf(z, wv.x, bv.x));
            g[i + 1] = (__bf16)gelu_exact(fmaf(z, wv.y, bv.y));
            g[i + 2] = (__bf16)gelu_exact(fmaf(z, wv.z, bv.z));
            g[i + 3] = (__bf16)gelu_exact(fmaf(z, wv.w, bv.w));
        }
        uint4* dst = reinterpret_cast<uint4*>(hidden + (size_t)s * HH + h0);
        const uint4* gg = reinterpret_cast<const uint4*>(g);
        dst[0] = gg[0];
        dst[1] = gg[1];
        return;
    }

    // histogram path
    __shared__ int shist[KK];
    const int j = blockIdx.x - BB / 16;
    if (tid < KK) shist[tid] = 0;
    __syncthreads();
    atomicAdd(&shist[head_idx[j * 256 + tid]], 1);
    __syncthreads();
    if (tid < KK) hist[j * KK + tid] = shist[tid];
}

// Kernel B: single 128-thread block. Reduce 16 histograms -> offsets (K+1)
// via exclusive scan, and per-scatter-block bases base[j][k].
__global__ __launch_bounds__(128) void scan_kernel(
    const int* __restrict__ hist, int* __restrict__ offsets,
    int* __restrict__ base)
{
    __shared__ int buf[128];
    const int t = threadIdx.x;
    int tot = 0;
    if (t < KK) {
#pragma unroll
        for (int j = 0; j < NHB; ++j) tot += hist[j * KK + t];
    }
    buf[t] = tot;
    __syncthreads();
    for (int d = 1; d < 128; d <<= 1) {
        int x = (t >= d) ? buf[t - d] : 0;
        __syncthreads();
        buf[t] += x;
        __syncthreads();
    }
    if (t < KK) {
        int acc = buf[t] - tot;          // exclusive prefix over heads
        offsets[t] = acc;
        if (t == KK - 1) offsets[KK] = buf[t];
#pragma unroll
        for (int j = 0; j < NHB; ++j) {  // prefix over scatter blocks
            base[j * KK + t] = acc;
            acc += hist[j * KK + t];
        }
    }
}

// Kernel C: 16 blocks scatter sample ids into buckets; cursors seeded from
// base[j][*], LDS atomics local to each block. Bucket order within a
// (block, head) group is nondeterministic; output values don't depend on it.
__global__ __launch_bounds__(256) void scatter_kernel(
    const int* __restrict__ head_idx, const int* __restrict__ base,
    int* __restrict__ bucket)
{
    __shared__ int cur[KK];
    const int j = blockIdx.x;
    const int tid = threadIdx.x;
    if (tid < KK) cur[tid] = base[j * KK + tid];
    __syncthreads();
    const int b = j * 256 + tid;
    const int pos = atomicAdd(&cur[head_idx[b]], 1);
    bucket[pos] = b;
}

// Kernel D: bucketed GEMM via bf16 MFMA 16x16x32.
// grid = (K, MAXT). Block 256 thr = 4 waves; wave w -> e-slice [64w, 64w+64).
// A = hidden tile (LDS, XOR-swizzled), B = W rows from global fp32 -> bf16.
__global__ __launch_bounds__(256) void head_gemm_mfma(
    const __bf16* __restrict__ hidden, const int* __restrict__ bucket,
    const int* __restrict__ offsets, const float* __restrict__ W_heads,
    const float* __restrict__ b_heads, float* __restrict__ out)
{
    const int k    = blockIdx.x;
    const int beg  = offsets[k];
    const int nk   = offsets[k + 1] - beg;
    const int tid  = threadIdx.x;
    const int wave = tid >> 6;
    const int lane = tid & 63;
    const int col16 = lane & 15;     // e within 16-frag / A row
    const int kch   = lane >> 4;     // k-chunk group
    const int wave_e = wave * 64;
    const float* __restrict__ Wk = W_heads + (size_t)k * (HH * EE);

    __shared__ __align__(16) __bf16 A_lds[16 * HH];  // 8 KB
    __shared__ int sids[16];

    for (int t = blockIdx.y; t * 16 < nk; t += gridDim.y) {
        __syncthreads();   // protect A_lds/sids from previous iteration readers
        if (tid < 16) {
            int idx = t * 16 + tid;
            if (idx >= nk) idx = nk - 1;   // clamp; masked at store
            sids[tid] = bucket[beg + idx];
        }
        __syncthreads();
        {   // stage A tile: 16 samples x 256 h bf16, 16B chunks, XOR swizzle
            const int s = tid >> 4, c = tid & 15;
            const uint4* src = reinterpret_cast<const uint4*>(hidden + (size_t)sids[s] * HH);
            const uint4 v0 = src[c];
            const uint4 v1 = src[c + 16];
            char* basep = reinterpret_cast<char*>(A_lds) + s * 512;
            *reinterpret_cast<uint4*>(basep + ((c        ^ (s & 7)) * 16)) = v0;
            *reinterpret_cast<uint4*>(basep + (((c + 16) ^ (s & 7)) * 16)) = v1;
        }
        __syncthreads();

        f32x4 acc[4];
#pragma unroll
        for (int nf = 0; nf < 4; ++nf) {
            const float bv = b_heads[k * EE + wave_e + nf * 16 + col16];
            acc[nf] = (f32x4){bv, bv, bv, bv};
        }

        const char* arow = reinterpret_cast<const char*>(A_lds) + col16 * 512;
#pragma unroll
        for (int kk = 0; kk < 8; ++kk) {
            // A-frag: row = lane&15, k = kk*32 + kch*8 + j  (8 consecutive bf16)
            const bf16x8 a = *reinterpret_cast<const bf16x8*>(
                arow + (((kk * 4 + kch) ^ (lane & 7)) * 16));
            const float* wbase = Wk + (size_t)(kk * 32 + kch * 8) * EE + wave_e + col16;
#pragma unroll
            for (int nf = 0; nf < 4; ++nf) {
                const float* wp = wbase + nf * 16;
                bf16x8 b;
#pragma unroll
                for (int jj = 0; jj < 8; ++jj) b[jj] = (__bf16)wp[jj * EE];
                acc[nf] = __builtin_amdgcn_mfma_f32_16x16x32_bf16(a, b, acc[nf], 0, 0, 0);
            }
        }

        // D layout: col = lane&15, row = (lane>>4)*4 + reg
#pragma unroll
        for (int r = 0; r < 4; ++r) {
            const int srow = kch * 4 + r;
            if (t * 16 + srow < nk) {
                float* op = out + (size_t)sids[srow] * EE + wave_e + col16;
#pragma unroll
                for (int nf = 0; nf < 4; ++nf) op[nf * 16] = acc[nf][r];
            }
        }
    }
}

// Fallback (only if ws too small): one block per sample, fp32.
__global__ __launch_bounds__(256) void fallback_kernel(
    const float* __restrict__ values, const float* __restrict__ means,
    const float* __restrict__ stds, const int* __restrict__ head_idx,
    const float* __restrict__ w1, const float* __restrict__ b1,
    const float* __restrict__ W_heads, const float* __restrict__ b_heads,
    float* __restrict__ out)
{
    __shared__ float hid[HH];
    const int b = blockIdx.x;
    const int t = threadIdx.x;
    const float z = norm_clip(values[b], means[b], stds[b]);
    hid[t] = gelu_exact(fmaf(z, w1[t], b1[t]));
    __syncthreads();
    const int k = head_idx[b];
    const float* __restrict__ Wk = W_heads + (size_t)k * (HH * EE);
    float acc = b_heads[k * EE + t];
    for (int h = 0; h < HH; ++h) acc = fmaf(hid[h], Wk[h * EE + t], acc);
    out[(size_t)b * EE + t] = acc;
}

extern "C" void kernel_launch(void* const* d_in, const int* in_sizes, int n_in,
                              void* d_out, int out_size, void* d_ws, size_t ws_size,
                              hipStream_t stream)
{
    const float* values   = (const float*)d_in[0];
    const float* means    = (const float*)d_in[1];
    const float* stds     = (const float*)d_in[2];
    const int*   head_idx = (const int*)d_in[3];
    const float* w1       = (const float*)d_in[4];
    const float* b1       = (const float*)d_in[5];
    const float* W_heads  = (const float*)d_in[6];
    const float* b_heads  = (const float*)d_in[7];
    float* out = (float*)d_out;

    // Workspace layout (bytes):
    //   [0,512)        offsets (K+1 ints)
    //   [512,8192)     hist   (16*100 ints = 6400 B)
    //   [8192,16384)   base   (16*100 ints)
    //   [16384,32768)  bucket (B ints)
    //   [32768,...)    hidden (B*H bf16 = 2 MB)
    const size_t need = 32768 + (size_t)BB * HH * sizeof(__bf16);
    if (ws_size >= need) {
        char* ws = (char*)d_ws;
        int*    offsets = (int*)(ws + 0);
        int*    hist    = (int*)(ws + 512);
        int*    base    = (int*)(ws + 8192);
        int*    bucket  = (int*)(ws + 16384);
        __bf16* hidden  = (__bf16*)(ws + 32768);

        hidden_hist_kernel<<<BB / 16 + NHB, 256, 0, stream>>>(
            values, means, stds, head_idx, w1, b1, hidden, hist);
        scan_kernel<<<1, 128, 0, stream>>>(hist, offsets, base);
        scatter_kernel<<<NHB, 256, 0, stream>>>(head_idx, base, bucket);
        head_gemm_mfma<<<dim3(KK, MAXT), 256, 0, stream>>>(
            hidden, bucket, offsets, W_heads, b_heads, out);
    } else {
        fallback_kernel<<<BB, 256, 0, stream>>>(values, means, stds, head_idx,
                                                w1, b1, W_heads, b_heads, out);
    }
}

// Round 5
// 23.680 us; speedup vs baseline: 1.2036x; 1.2036x over previous
//
#include <hip/hip_runtime.h>
#include <hip/hip_bf16.h>
#include <math.h>

// Problem constants (match reference: B=4096, H=256, E=256, K=100)
#define BB 4096
#define HH 256
#define EE 256
#define KK 100
#define NHB 16     // histogram/scatter blocks (256 samples each)
#define ET 4       // e-slices per head (W-stationary blocks)
#define ESL (EE / ET)   // 64 e-columns per slice

typedef __bf16 bf16x8 __attribute__((ext_vector_type(8)));
typedef float  f32x4  __attribute__((ext_vector_type(4)));

__device__ __forceinline__ float gelu_exact(float x) {
    return 0.5f * x * (1.0f + erff(x * 0.70710678118654752f));
}

__device__ __forceinline__ float norm_clip(float v, float m, float sd) {
    float z = (v - m) / fmaxf(sd, 1e-8f);
    return fminf(5.0f, fmaxf(-5.0f, z));
}

// Kernel A: blocks 0..255 -> hidden = gelu(z*w1+b1) in bf16 (16 samples each);
// blocks 256..271 -> private 100-bin histogram of 256 samples (LDS only).
__global__ __launch_bounds__(256) void hidden_hist_kernel(
    const float* __restrict__ values, const float* __restrict__ means,
    const float* __restrict__ stds, const int* __restrict__ head_idx,
    const float* __restrict__ w1, const float* __restrict__ b1,
    __bf16* __restrict__ hidden, int* __restrict__ hist)
{
    const int tid = threadIdx.x;

    if (blockIdx.x < BB / 16) {
        const int s  = blockIdx.x * 16 + (tid >> 4);
        const int h0 = (tid & 15) * 16;
        const float z = norm_clip(values[s], means[s], stds[s]);
        alignas(16) __bf16 g[16];
#pragma unroll
        for (int i = 0; i < 16; i += 4) {
            const float4 wv = *reinterpret_cast<const float4*>(w1 + h0 + i);
            const float4 bv = *reinterpret_cast<const float4*>(b1 + h0 + i);
            g[i + 0] = (__bf16)gelu_exact(fmaf(z, wv.x, bv.x));
            g[i + 1] = (__bf16)gelu_exact(fmaf(z, wv.y, bv.y));
            g[i + 2] = (__bf16)gelu_exact(fmaf(z, wv.z, bv.z));
            g[i + 3] = (__bf16)gelu_exact(fmaf(z, wv.w, bv.w));
        }
        uint4* dst = reinterpret_cast<uint4*>(hidden + (size_t)s * HH + h0);
        const uint4* gg = reinterpret_cast<const uint4*>(g);
        dst[0] = gg[0];
        dst[1] = gg[1];
        return;
    }

    __shared__ int shist[KK];
    const int j = blockIdx.x - BB / 16;
    if (tid < KK) shist[tid] = 0;
    __syncthreads();
    atomicAdd(&shist[head_idx[j * 256 + tid]], 1);
    __syncthreads();
    if (tid < KK) hist[j * KK + tid] = shist[tid];
}

// Kernel B: 16 blocks. Each redundantly reduces the 16 histograms and scans
// to get its own cursor bases (saves a separate scan node); block 0 also
// writes offsets for the gemm. Then scatters its 256 sample ids.
// Bucket order within a (block, head) group is nondeterministic; output
// values don't depend on it.
__global__ __launch_bounds__(256) void scatter_scan_kernel(
    const int* __restrict__ head_idx, const int* __restrict__ hist,
    int* __restrict__ offsets, int* __restrict__ bucket)
{
    __shared__ int sh[NHB * KK];
    __shared__ int buf[128];
    __shared__ int cur[KK];
    const int j = blockIdx.x;
    const int tid = threadIdx.x;

    for (int i = tid; i < NHB * KK; i += 256) sh[i] = hist[i];
    __syncthreads();

    int tot = 0, below = 0;
    if (tid < KK) {
#pragma unroll
        for (int jj = 0; jj < NHB; ++jj) {
            const int h = sh[jj * KK + tid];
            tot += h;
            if (jj < j) below += h;
        }
    }
    if (tid < 128) buf[tid] = (tid < KK) ? tot : 0;
    __syncthreads();
    for (int d = 1; d < 128; d <<= 1) {
        int x = (tid < 128 && tid >= d) ? buf[tid - d] : 0;
        __syncthreads();
        if (tid < 128) buf[tid] += x;
        __syncthreads();
    }
    if (tid < KK) {
        const int excl = buf[tid] - tot;   // exclusive prefix over heads
        cur[tid] = excl + below;
        if (j == 0) {
            offsets[tid] = excl;
            if (tid == KK - 1) offsets[KK] = buf[tid];
        }
    }
    __syncthreads();

    const int b = j * 256 + tid;
    const int pos = atomicAdd(&cur[head_idx[b]], 1);
    bucket[pos] = b;
}

// Kernel C: W-stationary bucketed GEMM, bf16 MFMA 16x16x32.
// grid = (K, ET). Block (k, et): stage W[k][:, et*64..+64) ONCE into LDS as
// transposed + XOR-swizzled bf16 (32 KB), then loop s-tiles of head k.
// A-frags: per-lane 16B gathers from hidden (L2/L3-warm). B-frags: one
// conflict-free ds_read_b128 each. Store sids recovered via __shfl.
__global__ __launch_bounds__(256) void head_gemm_mfma(
    const __bf16* __restrict__ hidden, const int* __restrict__ bucket,
    const int* __restrict__ offsets, const float* __restrict__ W_heads,
    const float* __restrict__ b_heads, float* __restrict__ out)
{
    const int k    = blockIdx.x;
    const int et   = blockIdx.y;
    const int tid  = threadIdx.x;
    const int wave = tid >> 6;
    const int lane = tid & 63;
    const int col16 = lane & 15;
    const int kch   = lane >> 4;
    const int beg = offsets[k];
    const int nk  = offsets[k + 1] - beg;
    const float* __restrict__ Wk = W_heads + (size_t)k * (HH * EE) + et * ESL;

    // Wt: transposed W-slice, e-major rows of 256 bf16 (512 B), 16B chunks
    // XOR-swizzled by (e&7). Element (k_g, e): byte = e*512 +
    // ((k_g>>3)^(e&7))*16 + (k_g&7)*2.
    __shared__ __align__(16) __bf16 Wt[ESL * HH];   // 32 KB

    {   // stage: 16 rounds; thread -> (k-row rr*16 + tid>>4, 4 e-cols)
        const int rsub = tid >> 4;
        const int e0   = (tid & 15) * 4;
        char* basep = reinterpret_cast<char*>(Wt);
#pragma unroll 4
        for (int rr = 0; rr < 16; ++rr) {
            const int r = rr * 16 + rsub;
            const float4 wv = *reinterpret_cast<const float4*>(Wk + r * EE + e0);
            const float* wvp = &wv.x;
#pragma unroll
            for (int i = 0; i < 4; ++i) {
                const int e = e0 + i;
                const int byte = e * 512 + (((r >> 3) ^ (e & 7)) << 4) + ((r & 7) << 1);
                *reinterpret_cast<__bf16*>(basep + byte) = (__bf16)wvp[i];
            }
        }
    }
    __syncthreads();
    if (nk == 0) return;

    float bias[4];
#pragma unroll
    for (int nf = 0; nf < 4; ++nf)
        bias[nf] = b_heads[k * EE + et * ESL + nf * 16 + col16];

    const char* wtp = reinterpret_cast<const char*>(Wt);

    for (int t = wave; t * 16 < nk; t += 4) {
        int idx = t * 16 + col16;
        if (idx >= nk) idx = nk - 1;      // clamp; masked at store
        const int sid = bucket[beg + idx];
        const __bf16* hrow = hidden + (size_t)sid * HH;

        f32x4 acc[4];
#pragma unroll
        for (int nf = 0; nf < 4; ++nf)
            acc[nf] = (f32x4){bias[nf], bias[nf], bias[nf], bias[nf]};

#pragma unroll
        for (int kk = 0; kk < 8; ++kk) {
            const bf16x8 a = *reinterpret_cast<const bf16x8*>(hrow + kk * 32 + kch * 8);
            const int chunk = kk * 4 + kch;
#pragma unroll
            for (int nf = 0; nf < 4; ++nf) {
                const int e = nf * 16 + col16;
                const bf16x8 b = *reinterpret_cast<const bf16x8*>(
                    wtp + e * 512 + ((chunk ^ (e & 7)) << 4));
                acc[nf] = __builtin_amdgcn_mfma_f32_16x16x32_bf16(a, b, acc[nf], 0, 0, 0);
            }
        }

        // D layout: col = lane&15 (e), row = kch*4 + reg (sample slot)
#pragma unroll
        for (int r = 0; r < 4; ++r) {
            const int srow = kch * 4 + r;
            const int sidr = __shfl(sid, srow);   // lane srow holds sids[srow]
            if (t * 16 + srow < nk) {
                float* op = out + (size_t)sidr * EE + et * ESL + col16;
#pragma unroll
                for (int nf = 0; nf < 4; ++nf) op[nf * 16] = acc[nf][r];
            }
        }
    }
}

// Fallback (only if ws too small): one block per sample, fp32.
__global__ __launch_bounds__(256) void fallback_kernel(
    const float* __restrict__ values, const float* __restrict__ means,
    const float* __restrict__ stds, const int* __restrict__ head_idx,
    const float* __restrict__ w1, const float* __restrict__ b1,
    const float* __restrict__ W_heads, const float* __restrict__ b_heads,
    float* __restrict__ out)
{
    __shared__ float hid[HH];
    const int b = blockIdx.x;
    const int t = threadIdx.x;
    const float z = norm_clip(values[b], means[b], stds[b]);
    hid[t] = gelu_exact(fmaf(z, w1[t], b1[t]));
    __syncthreads();
    const int k = head_idx[b];
    const float* __restrict__ Wk = W_heads + (size_t)k * (HH * EE);
    float acc = b_heads[k * EE + t];
    for (int h = 0; h < HH; ++h) acc = fmaf(hid[h], Wk[h * EE + t], acc);
    out[(size_t)b * EE + t] = acc;
}

extern "C" void kernel_launch(void* const* d_in, const int* in_sizes, int n_in,
                              void* d_out, int out_size, void* d_ws, size_t ws_size,
                              hipStream_t stream)
{
    const float* values   = (const float*)d_in[0];
    const float* means    = (const float*)d_in[1];
    const float* stds     = (const float*)d_in[2];
    const int*   head_idx = (const int*)d_in[3];
    const float* w1       = (const float*)d_in[4];
    const float* b1       = (const float*)d_in[5];
    const float* W_heads  = (const float*)d_in[6];
    const float* b_heads  = (const float*)d_in[7];
    float* out = (float*)d_out;

    // Workspace layout (bytes):
    //   [0,512)        offsets (K+1 ints)
    //   [1024,7424)    hist   (16*100 ints)
    //   [8192,24576)   bucket (B ints)
    //   [32768,...)    hidden (B*H bf16 = 2 MB)
    const size_t need = 32768 + (size_t)BB * HH * sizeof(__bf16);
    if (ws_size >= need) {
        char* ws = (char*)d_ws;
        int*    offsets = (int*)(ws + 0);
        int*    hist    = (int*)(ws + 1024);
        int*    bucket  = (int*)(ws + 8192);
        __bf16* hidden  = (__bf16*)(ws + 32768);

        hidden_hist_kernel<<<BB / 16 + NHB, 256, 0, stream>>>(
            values, means, stds, head_idx, w1, b1, hidden, hist);
        scatter_scan_kernel<<<NHB, 256, 0, stream>>>(head_idx, hist, offsets, bucket);
        head_gemm_mfma<<<dim3(KK, ET), 256, 0, stream>>>(
            hidden, bucket, offsets, W_heads, b_heads, out);
    } else {
        fallback_kernel<<<BB, 256, 0, stream>>>(values, means, stds, head_idx,
                                                w1, b1, W_heads, b_heads, out);
    }
}

// Round 6
// 20.248 us; speedup vs baseline: 1.4075x; 1.1695x over previous
//
#include <hip/hip_runtime.h>
#include <hip/hip_bf16.h>
#include <math.h>

// Problem constants (match reference: B=4096, H=256, E=256, K=100)
#define BB 4096
#define HH 256
#define EE 256
#define KK 100

typedef __bf16 bf16x8 __attribute__((ext_vector_type(8)));
typedef float  f32x4  __attribute__((ext_vector_type(4)));

__device__ __forceinline__ float gelu_exact(float x) {
    // torch nn.GELU default: 0.5*x*(1+erf(x/sqrt(2)))
    return 0.5f * x * (1.0f + erff(x * 0.70710678118654752f));
}

__device__ __forceinline__ float norm_clip(float v, float m, float sd) {
    float z = (v - m) / fmaxf(sd, 1e-8f);
    return fminf(5.0f, fmaxf(-5.0f, z));
}

// Single fused kernel. grid = (K, 4). Block (k, et) owns output columns
// [et*64, et*64+64); wave w owns the 16-e substrip et*64+w*16..+16.
//   Phase 1: W-strip -> registers as MFMA B-frags (stride-1KB dword loads,
//            64B/16-lane segments; W read EXACTLY once chip-wide).
//   Phase 2: ballot-compact this head's sample ids from head_idx into LDS.
//   Phase 3: per 64-sample chunk, compute hidden=gelu(z*w1+b1) in bf16
//            straight into XOR-swizzled LDS (no global round-trip).
//   Phase 4: per 16-sample tile per wave: 8 chained mfma_16x16x32_bf16,
//            masked coalesced stores.
// Sample-slot order from LDS atomics is nondeterministic, but each output
// element = bias + sum_h hid[s][h]*W[h][e] with fixed k-order regardless of
// slot -> output bit-deterministic.
__global__ __launch_bounds__(256, 2) void fused_kernel(
    const float* __restrict__ values, const float* __restrict__ means,
    const float* __restrict__ stds, const int* __restrict__ head_idx,
    const float* __restrict__ w1, const float* __restrict__ b1,
    const float* __restrict__ W_heads, const float* __restrict__ b_heads,
    float* __restrict__ out)
{
    const int k    = blockIdx.x;
    const int et   = blockIdx.y;
    const int tid  = threadIdx.x;
    const int wave = tid >> 6;
    const int lane = tid & 63;
    const int col16 = lane & 15;   // e within 16-strip / D column
    const int kch   = lane >> 4;   // k-chunk group (8 consecutive k each)
    const int e = et * 64 + wave * 16 + col16;   // this lane's output column

    __shared__ int sl[BB];                        // 16 KB (worst-case safe)
    __shared__ int s_nk;
    __shared__ __align__(16) __bf16 hid[64 * HH]; // 32 KB, XOR-swizzled

    // ---- Phase 1: issue W loads (held as fp32 across phase 2) ----
    float wf[8][8];
    {
        const float* __restrict__ Wke = W_heads + (size_t)k * (HH * EE) + e;
#pragma unroll
        for (int kk = 0; kk < 8; ++kk)
#pragma unroll
            for (int j = 0; j < 8; ++j)
                wf[kk][j] = Wke[(size_t)(kk * 32 + kch * 8 + j) * EE];
    }

    // ---- Phase 2: compact sample ids of head k into sl[] ----
    if (tid == 0) s_nk = 0;
    __syncthreads();
#pragma unroll 1
    for (int i = 0; i < BB / 256; ++i) {
        const int b = i * 256 + tid;
        const bool m = (head_idx[b] == k);
        const unsigned long long mask = __ballot(m);
        const int cnt = __popcll(mask);
        int base = 0;
        if (lane == 0 && cnt) base = atomicAdd(&s_nk, cnt);
        base = __shfl(base, 0);
        if (m) sl[base + __popcll(mask & ((1ull << lane) - 1))] = b;
    }
    __syncthreads();
    const int nk = s_nk;
    if (nk == 0) return;

    // ---- Phase 3 prep: convert W to bf16 B-frags; bias ----
    bf16x8 wb[8];
#pragma unroll
    for (int kk = 0; kk < 8; ++kk)
#pragma unroll
        for (int j = 0; j < 8; ++j)
            wb[kk][j] = (__bf16)wf[kk][j];
    const float bias = b_heads[k * EE + e];

    // hid staging mapping: thread (rsub, cch) writes row rr*16+rsub,
    // 16B chunks cch and cch+16 (elements h = c*8..c*8+8).
    const int rsub = tid >> 4;
    const int cch  = tid & 15;
    const float4 w1a = *reinterpret_cast<const float4*>(w1 + cch * 8);
    const float4 w1b = *reinterpret_cast<const float4*>(w1 + cch * 8 + 4);
    const float4 w1c = *reinterpret_cast<const float4*>(w1 + cch * 8 + 128);
    const float4 w1d = *reinterpret_cast<const float4*>(w1 + cch * 8 + 132);
    const float4 b1a = *reinterpret_cast<const float4*>(b1 + cch * 8);
    const float4 b1b = *reinterpret_cast<const float4*>(b1 + cch * 8 + 4);
    const float4 b1c = *reinterpret_cast<const float4*>(b1 + cch * 8 + 128);
    const float4 b1d = *reinterpret_cast<const float4*>(b1 + cch * 8 + 132);

    char* const hidp = reinterpret_cast<char*>(hid);

    for (int c0 = 0; c0 < nk; c0 += 64) {
        __syncthreads();   // protect hid from previous chunk's readers
#pragma unroll
        for (int rr = 0; rr < 4; ++rr) {
            const int s_loc = rr * 16 + rsub;
            int gi = c0 + s_loc;
            if (gi >= nk) gi = nk - 1;           // clamp; masked at store
            const int sid = sl[gi];
            const float z = norm_clip(values[sid], means[sid], stds[sid]);
            bf16x8 lo, hi;
            lo[0] = (__bf16)gelu_exact(fmaf(z, w1a.x, b1a.x));
            lo[1] = (__bf16)gelu_exact(fmaf(z, w1a.y, b1a.y));
            lo[2] = (__bf16)gelu_exact(fmaf(z, w1a.z, b1a.z));
            lo[3] = (__bf16)gelu_exact(fmaf(z, w1a.w, b1a.w));
            lo[4] = (__bf16)gelu_exact(fmaf(z, w1b.x, b1b.x));
            lo[5] = (__bf16)gelu_exact(fmaf(z, w1b.y, b1b.y));
            lo[6] = (__bf16)gelu_exact(fmaf(z, w1b.z, b1b.z));
            lo[7] = (__bf16)gelu_exact(fmaf(z, w1b.w, b1b.w));
            hi[0] = (__bf16)gelu_exact(fmaf(z, w1c.x, b1c.x));
            hi[1] = (__bf16)gelu_exact(fmaf(z, w1c.y, b1c.y));
            hi[2] = (__bf16)gelu_exact(fmaf(z, w1c.z, b1c.z));
            hi[3] = (__bf16)gelu_exact(fmaf(z, w1c.w, b1c.w));
            hi[4] = (__bf16)gelu_exact(fmaf(z, w1d.x, b1d.x));
            hi[5] = (__bf16)gelu_exact(fmaf(z, w1d.y, b1d.y));
            hi[6] = (__bf16)gelu_exact(fmaf(z, w1d.z, b1d.z));
            hi[7] = (__bf16)gelu_exact(fmaf(z, w1d.w, b1d.w));
            char* bp = hidp + s_loc * 512;
            *reinterpret_cast<bf16x8*>(bp + ((cch        ^ (s_loc & 7)) << 4)) = lo;
            *reinterpret_cast<bf16x8*>(bp + (((cch + 16) ^ (s_loc & 7)) << 4)) = hi;
        }
        __syncthreads();

        const int ntt = min(4, (nk - c0 + 15) >> 4);
        for (int tt = 0; tt < ntt; ++tt) {
            const int row = tt * 16 + col16;
            const char* ap = hidp + row * 512;
            f32x4 acc = (f32x4){bias, bias, bias, bias};
#pragma unroll
            for (int kk = 0; kk < 8; ++kk) {
                const bf16x8 a = *reinterpret_cast<const bf16x8*>(
                    ap + (((kk * 4 + kch) ^ (row & 7)) << 4));
                acc = __builtin_amdgcn_mfma_f32_16x16x32_bf16(a, wb[kk], acc, 0, 0, 0);
            }
            // D layout: col = lane&15 (e), row = kch*4 + r (sample slot)
            const int sbase = c0 + tt * 16 + kch * 4;
#pragma unroll
            for (int r = 0; r < 4; ++r) {
                if (sbase + r < nk)
                    out[(size_t)sl[sbase + r] * EE + e] = acc[r];
            }
        }
    }
}

extern "C" void kernel_launch(void* const* d_in, const int* in_sizes, int n_in,
                              void* d_out, int out_size, void* d_ws, size_t ws_size,
                              hipStream_t stream)
{
    const float* values   = (const float*)d_in[0];
    const float* means    = (const float*)d_in[1];
    const float* stds     = (const float*)d_in[2];
    const int*   head_idx = (const int*)d_in[3];
    const float* w1       = (const float*)d_in[4];
    const float* b1       = (const float*)d_in[5];
    const float* W_heads  = (const float*)d_in[6];
    const float* b_heads  = (const float*)d_in[7];
    float* out = (float*)d_out;

    fused_kernel<<<dim3(KK, 4), 256, 0, stream>>>(
        values, means, stds, head_idx, w1, b1, W_heads, b_heads, out);
}

// Round 7
// 17.244 us; speedup vs baseline: 1.6528x; 1.1742x over previous
//
#include <hip/hip_runtime.h>
#include <hip/hip_bf16.h>
#include <math.h>

// Problem constants (match reference: B=4096, H=256, E=256, K=100)
#define BB 4096
#define HH 256
#define EE 256
#define KK 100

typedef __bf16 bf16x8 __attribute__((ext_vector_type(8)));
typedef float  f32x4  __attribute__((ext_vector_type(4)));

// tanh-form GELU (|err vs exact erf-GELU| < ~3e-3; bf16 rounding dominates).
// tanh(y) = 1 - 2/(exp(2y)+1); __expf handles over/underflow (inf/0) cleanly.
__device__ __forceinline__ float gelu_fast(float x) {
    const float x3 = x * x * x;
    const float y2 = fmaf(0.044715f, x3, x) * 1.5957691216057308f;  // 2*sqrt(2/pi)*(...)
    const float e  = __expf(y2);
    const float t  = 1.0f - 2.0f / (e + 1.0f);
    return 0.5f * x * (1.0f + t);
}

__device__ __forceinline__ float norm_clip(float v, float m, float sd) {
    float z = (v - m) / fmaxf(sd, 1e-8f);
    return fminf(5.0f, fmaxf(-5.0f, z));
}

// Single fused kernel. grid = (K, 4). Block (k, et) owns output columns
// [et*64, et*64+64); wave w owns the 16-e substrip et*64+w*16..+16.
//   Phase 1: W-strip -> registers (stride-1KB dword loads; W read once chip-wide).
//   Phase 2: DETERMINISTIC atomic-free ballot-compaction of head-k sample ids
//            (all loads upfront, 16 ballots, (round,wave) count matrix in LDS,
//            register prefix scan -> bucket sorted by sample id).
//   Phase 3: per 64-sample chunk, hidden = gelu(z*w1+b1) bf16 -> swizzled LDS,
//            skipping 16-row rounds entirely past nk.
//   Phase 4: 8 chained mfma_16x16x32_bf16 per 16-sample tile, masked stores.
__global__ __launch_bounds__(256, 3) void fused_kernel(
    const float* __restrict__ values, const float* __restrict__ means,
    const float* __restrict__ stds, const int* __restrict__ head_idx,
    const float* __restrict__ w1, const float* __restrict__ b1,
    const float* __restrict__ W_heads, const float* __restrict__ b_heads,
    float* __restrict__ out)
{
    const int k    = blockIdx.x;
    const int et   = blockIdx.y;
    const int tid  = threadIdx.x;
    const int wave = tid >> 6;
    const int lane = tid & 63;
    const int col16 = lane & 15;   // e within 16-strip / D column
    const int kch   = lane >> 4;   // k-chunk group (8 consecutive k each)
    const int e = et * 64 + wave * 16 + col16;   // this lane's output column

    __shared__ int sl[BB];                        // 16 KB (worst-case safe)
    __shared__ int cnt_lds[64];                   // [round i][wave w] = i*4+w
    __shared__ __align__(16) __bf16 hid[64 * HH]; // 32 KB, XOR-swizzled

    // ---- Phase 1: issue W loads (held as fp32 across phase 2) ----
    float wf[8][8];
    {
        const float* __restrict__ Wke = W_heads + (size_t)k * (HH * EE) + e;
#pragma unroll
        for (int kk = 0; kk < 8; ++kk)
#pragma unroll
            for (int j = 0; j < 8; ++j)
                wf[kk][j] = Wke[(size_t)(kk * 32 + kch * 8 + j) * EE];
    }

    // ---- Phase 2: deterministic ballot-compaction ----
    int h16[16];
#pragma unroll
    for (int i = 0; i < 16; ++i) h16[i] = head_idx[i * 256 + tid];
    unsigned long long msk[16];
#pragma unroll
    for (int i = 0; i < 16; ++i) {
        msk[i] = __ballot(h16[i] == k);
        if (lane == 0) cnt_lds[i * 4 + wave] = __popcll(msk[i]);
    }
    __syncthreads();
    int base[16];
    int run = 0;
#pragma unroll
    for (int i = 0; i < 16; ++i) {
        int b0 = run;
#pragma unroll
        for (int w2 = 0; w2 < 4; ++w2) {
            if (w2 == wave) base[i] = b0;
            b0 += cnt_lds[i * 4 + w2];
        }
        run = b0;
    }
    const int nk = run;
    if (nk == 0) return;
#pragma unroll
    for (int i = 0; i < 16; ++i) {
        if (h16[i] == k) {
            const int pos = base[i] + __popcll(msk[i] & ((1ull << lane) - 1));
            sl[pos] = i * 256 + tid;
        }
    }
    __syncthreads();

    // ---- convert W to bf16 B-frags; bias ----
    bf16x8 wb[8];
#pragma unroll
    for (int kk = 0; kk < 8; ++kk)
#pragma unroll
        for (int j = 0; j < 8; ++j)
            wb[kk][j] = (__bf16)wf[kk][j];
    const float bias = b_heads[k * EE + e];

    // hid staging mapping: thread (rsub, cch) writes row rr*16+rsub,
    // 16B chunks cch and cch+16 (elements h = chunk*8..+8).
    const int rsub = tid >> 4;
    const int cch  = tid & 15;
    const float4 w1a = *reinterpret_cast<const float4*>(w1 + cch * 8);
    const float4 w1b = *reinterpret_cast<const float4*>(w1 + cch * 8 + 4);
    const float4 w1c = *reinterpret_cast<const float4*>(w1 + cch * 8 + 128);
    const float4 w1d = *reinterpret_cast<const float4*>(w1 + cch * 8 + 132);
    const float4 b1a = *reinterpret_cast<const float4*>(b1 + cch * 8);
    const float4 b1b = *reinterpret_cast<const float4*>(b1 + cch * 8 + 4);
    const float4 b1c = *reinterpret_cast<const float4*>(b1 + cch * 8 + 128);
    const float4 b1d = *reinterpret_cast<const float4*>(b1 + cch * 8 + 132);

    char* const hidp = reinterpret_cast<char*>(hid);

    for (int c0 = 0; c0 < nk; c0 += 64) {
        __syncthreads();   // protect hid from previous chunk's readers
#pragma unroll
        for (int rr = 0; rr < 4; ++rr) {
            if (c0 + rr * 16 >= nk) break;       // rows past nk are never read
            const int s_loc = rr * 16 + rsub;
            int gi = c0 + s_loc;
            if (gi >= nk) gi = nk - 1;           // clamp; masked at store
            const int sid = sl[gi];
            const float z = norm_clip(values[sid], means[sid], stds[sid]);
            bf16x8 lo, hi;
            lo[0] = (__bf16)gelu_fast(fmaf(z, w1a.x, b1a.x));
            lo[1] = (__bf16)gelu_fast(fmaf(z, w1a.y, b1a.y));
            lo[2] = (__bf16)gelu_fast(fmaf(z, w1a.z, b1a.z));
            lo[3] = (__bf16)gelu_fast(fmaf(z, w1a.w, b1a.w));
            lo[4] = (__bf16)gelu_fast(fmaf(z, w1b.x, b1b.x));
            lo[5] = (__bf16)gelu_fast(fmaf(z, w1b.y, b1b.y));
            lo[6] = (__bf16)gelu_fast(fmaf(z, w1b.z, b1b.z));
            lo[7] = (__bf16)gelu_fast(fmaf(z, w1b.w, b1b.w));
            hi[0] = (__bf16)gelu_fast(fmaf(z, w1c.x, b1c.x));
            hi[1] = (__bf16)gelu_fast(fmaf(z, w1c.y, b1c.y));
            hi[2] = (__bf16)gelu_fast(fmaf(z, w1c.z, b1c.z));
            hi[3] = (__bf16)gelu_fast(fmaf(z, w1c.w, b1c.w));
            hi[4] = (__bf16)gelu_fast(fmaf(z, w1d.x, b1d.x));
            hi[5] = (__bf16)gelu_fast(fmaf(z, w1d.y, b1d.y));
            hi[6] = (__bf16)gelu_fast(fmaf(z, w1d.z, b1d.z));
            hi[7] = (__bf16)gelu_fast(fmaf(z, w1d.w, b1d.w));
            char* bp = hidp + s_loc * 512;
            *reinterpret_cast<bf16x8*>(bp + ((cch        ^ (s_loc & 7)) << 4)) = lo;
            *reinterpret_cast<bf16x8*>(bp + (((cch + 16) ^ (s_loc & 7)) << 4)) = hi;
        }
        __syncthreads();

        const int ntt = min(4, (nk - c0 + 15) >> 4);
        for (int tt = 0; tt < ntt; ++tt) {
            const int row = tt * 16 + col16;
            const char* ap = hidp + row * 512;
            f32x4 acc = (f32x4){bias, bias, bias, bias};
#pragma unroll
            for (int kk = 0; kk < 8; ++kk) {
                const bf16x8 a = *reinterpret_cast<const bf16x8*>(
                    ap + (((kk * 4 + kch) ^ (row & 7)) << 4));
                acc = __builtin_amdgcn_mfma_f32_16x16x32_bf16(a, wb[kk], acc, 0, 0, 0);
            }
            // D layout: col = lane&15 (e), row = kch*4 + r (sample slot)
            const int sbase = c0 + tt * 16 + kch * 4;
#pragma unroll
            for (int r = 0; r < 4; ++r) {
                if (sbase + r < nk)
                    out[(size_t)sl[sbase + r] * EE + e] = acc[r];
            }
        }
    }
}

extern "C" void kernel_launch(void* const* d_in, const int* in_sizes, int n_in,
                              void* d_out, int out_size, void* d_ws, size_t ws_size,
                              hipStream_t stream)
{
    const float* values   = (const float*)d_in[0];
    const float* means    = (const float*)d_in[1];
    const float* stds     = (const float*)d_in[2];
    const int*   head_idx = (const int*)d_in[3];
    const float* w1       = (const float*)d_in[4];
    const float* b1       = (const float*)d_in[5];
    const float* W_heads  = (const float*)d_in[6];
    const float* b_heads  = (const float*)d_in[7];
    float* out = (float*)d_out;

    fused_kernel<<<dim3(KK, 4), 256, 0, stream>>>(
        values, means, stds, head_idx, w1, b1, W_heads, b_heads, out);
}

// Round 8
// 15.167 us; speedup vs baseline: 1.8791x; 1.1370x over previous
//
#include <hip/hip_runtime.h>
#include <hip/hip_bf16.h>
#include <math.h>

// Problem constants (match reference: B=4096, H=256, E=256, K=100)
#define BB 4096
#define HH 256
#define EE 256
#define KK 100
#define SLMAX 2048   // bucket capacity (max realistic nk ~75 @ B/K=41)

typedef __bf16 bf16x8 __attribute__((ext_vector_type(8)));
typedef float  f32x4  __attribute__((ext_vector_type(4)));

// tanh-form GELU; 2/(e+1) via v_rcp_f32 (rel err ~1e-5, far below bf16 lsb).
__device__ __forceinline__ float gelu_fast(float x) {
    const float x3 = x * x * x;
    const float y2 = fmaf(0.044715f, x3, x) * 1.5957691216057308f;  // 2*sqrt(2/pi)*(..)
    const float e  = __expf(y2);
    const float t  = 1.0f - 2.0f * __builtin_amdgcn_rcpf(e + 1.0f);
    return 0.5f * x * (1.0f + t);
}

__device__ __forceinline__ float norm_clip(float v, float m, float sd) {
    float z = (v - m) / fmaxf(sd, 1e-8f);
    return fminf(5.0f, fmaxf(-5.0f, z));
}

// Single fused kernel. grid = (K, 4). Block (k, et) owns output columns
// [et*64, et*64+64); wave w owns e-substrip et*64+w*16..+16.
// Phase order chosen for register lifetime + latency cover:
//   A: deterministic ballot-compaction (h16/msk/base die here)
//   B: issue 64 W dword loads (wf)
//   C: gelu-stage chunk 0 into swizzled LDS (covers W-load drain)
//   D: convert wf -> bf16 B-frags (vmcnt waits land here, already covered)
//   E: MFMA tiles + masked stores; stage next chunk only if nk > 64 (rare)
__global__ __launch_bounds__(256, 3) void fused_kernel(
    const float* __restrict__ values, const float* __restrict__ means,
    const float* __restrict__ stds, const int* __restrict__ head_idx,
    const float* __restrict__ w1, const float* __restrict__ b1,
    const float* __restrict__ W_heads, const float* __restrict__ b_heads,
    float* __restrict__ out)
{
    const int k    = blockIdx.x;
    const int et   = blockIdx.y;
    const int tid  = threadIdx.x;
    const int wave = tid >> 6;
    const int lane = tid & 63;
    const int col16 = lane & 15;   // e within 16-strip / D column
    const int kch   = lane >> 4;   // k-chunk group (8 consecutive k each)
    const int e = et * 64 + wave * 16 + col16;   // this lane's output column

    __shared__ int sl[SLMAX];                     // 8 KB
    __shared__ int cnt_lds[64];                   // [round i][wave w]
    __shared__ __align__(16) __bf16 hid[64 * HH]; // 32 KB, XOR-swizzled

    // ---- Phase A: deterministic ballot-compaction ----
    int nk;
    {
        int h16[16];
#pragma unroll
        for (int i = 0; i < 16; ++i) h16[i] = head_idx[i * 256 + tid];
        unsigned long long msk[16];
#pragma unroll
        for (int i = 0; i < 16; ++i) {
            msk[i] = __ballot(h16[i] == k);
            if (lane == 0) cnt_lds[i * 4 + wave] = __popcll(msk[i]);
        }
        __syncthreads();
        int base[16];
        int run = 0;
#pragma unroll
        for (int i = 0; i < 16; ++i) {
            int b0 = run;
#pragma unroll
            for (int w2 = 0; w2 < 4; ++w2) {
                if (w2 == wave) base[i] = b0;
                b0 += cnt_lds[i * 4 + w2];
            }
            run = b0;
        }
        nk = run;
        if (nk == 0) return;
#pragma unroll
        for (int i = 0; i < 16; ++i) {
            if (h16[i] == k) {
                const int pos = base[i] + __popcll(msk[i] & ((1ull << lane) - 1));
                if (pos < SLMAX) sl[pos] = i * 256 + tid;
            }
        }
        if (nk > SLMAX) nk = SLMAX;
        __syncthreads();
    }

    // ---- Phase B: issue W loads (held fp32; converted in phase D) ----
    float wf[8][8];
    {
        const float* __restrict__ Wke = W_heads + (size_t)k * (HH * EE) + e;
#pragma unroll
        for (int kk = 0; kk < 8; ++kk)
#pragma unroll
            for (int j = 0; j < 8; ++j)
                wf[kk][j] = Wke[(size_t)(kk * 32 + kch * 8 + j) * EE];
    }
    const float bias = b_heads[k * EE + e];

    // hid staging mapping: thread (rsub, cch) writes row rr*16+rsub,
    // 16B chunks cch and cch+16 (elements h = chunk*8..+8).
    const int rsub = tid >> 4;
    const int cch  = tid & 15;
    const float4 w1a = *reinterpret_cast<const float4*>(w1 + cch * 8);
    const float4 w1b = *reinterpret_cast<const float4*>(w1 + cch * 8 + 4);
    const float4 w1c = *reinterpret_cast<const float4*>(w1 + cch * 8 + 128);
    const float4 w1d = *reinterpret_cast<const float4*>(w1 + cch * 8 + 132);
    const float4 b1a = *reinterpret_cast<const float4*>(b1 + cch * 8);
    const float4 b1b = *reinterpret_cast<const float4*>(b1 + cch * 8 + 4);
    const float4 b1c = *reinterpret_cast<const float4*>(b1 + cch * 8 + 128);
    const float4 b1d = *reinterpret_cast<const float4*>(b1 + cch * 8 + 132);

    char* const hidp = reinterpret_cast<char*>(hid);

    // Stage one 64-sample chunk of hidden into swizzled LDS (tail rows skipped;
    // stale LDS there is finite garbage, masked at the output store).
    auto stage = [&](int c0) {
#pragma unroll
        for (int rr = 0; rr < 4; ++rr) {
            if (c0 + rr * 16 >= nk) break;           // uniform
            const int s_loc = rr * 16 + rsub;
            const int gi = c0 + s_loc;
            if (gi < nk) {
                const int sid = sl[gi];
                const float z = norm_clip(values[sid], means[sid], stds[sid]);
                bf16x8 lo, hi;
                lo[0] = (__bf16)gelu_fast(fmaf(z, w1a.x, b1a.x));
                lo[1] = (__bf16)gelu_fast(fmaf(z, w1a.y, b1a.y));
                lo[2] = (__bf16)gelu_fast(fmaf(z, w1a.z, b1a.z));
                lo[3] = (__bf16)gelu_fast(fmaf(z, w1a.w, b1a.w));
                lo[4] = (__bf16)gelu_fast(fmaf(z, w1b.x, b1b.x));
                lo[5] = (__bf16)gelu_fast(fmaf(z, w1b.y, b1b.y));
                lo[6] = (__bf16)gelu_fast(fmaf(z, w1b.z, b1b.z));
                lo[7] = (__bf16)gelu_fast(fmaf(z, w1b.w, b1b.w));
                hi[0] = (__bf16)gelu_fast(fmaf(z, w1c.x, b1c.x));
                hi[1] = (__bf16)gelu_fast(fmaf(z, w1c.y, b1c.y));
                hi[2] = (__bf16)gelu_fast(fmaf(z, w1c.z, b1c.z));
                hi[3] = (__bf16)gelu_fast(fmaf(z, w1c.w, b1c.w));
                hi[4] = (__bf16)gelu_fast(fmaf(z, w1d.x, b1d.x));
                hi[5] = (__bf16)gelu_fast(fmaf(z, w1d.y, b1d.y));
                hi[6] = (__bf16)gelu_fast(fmaf(z, w1d.z, b1d.z));
                hi[7] = (__bf16)gelu_fast(fmaf(z, w1d.w, b1d.w));
                char* bp = hidp + s_loc * 512;
                *reinterpret_cast<bf16x8*>(bp + ((cch        ^ (s_loc & 7)) << 4)) = lo;
                *reinterpret_cast<bf16x8*>(bp + (((cch + 16) ^ (s_loc & 7)) << 4)) = hi;
            }
        }
    };

    // ---- Phase C: stage chunk 0 (covers W-load latency) ----
    stage(0);

    // ---- Phase D: convert W to bf16 B-frags (waits land here) ----
    bf16x8 wb[8];
#pragma unroll
    for (int kk = 0; kk < 8; ++kk)
#pragma unroll
        for (int j = 0; j < 8; ++j)
            wb[kk][j] = (__bf16)wf[kk][j];

    __syncthreads();

    // ---- Phase E: MFMA per chunk; stage next chunk only if needed ----
    for (int c0 = 0;; c0 += 64) {
        const int ntt = min(4, (nk - c0 + 15) >> 4);
        for (int tt = 0; tt < ntt; ++tt) {
            const int row = tt * 16 + col16;
            const char* ap = hidp + row * 512;
            f32x4 acc = (f32x4){bias, bias, bias, bias};
#pragma unroll
            for (int kk = 0; kk < 8; ++kk) {
                const bf16x8 a = *reinterpret_cast<const bf16x8*>(
                    ap + (((kk * 4 + kch) ^ (row & 7)) << 4));
                acc = __builtin_amdgcn_mfma_f32_16x16x32_bf16(a, wb[kk], acc, 0, 0, 0);
            }
            // D layout: col = lane&15 (e), row = kch*4 + r (sample slot)
            const int sbase = c0 + tt * 16 + kch * 4;
#pragma unroll
            for (int r = 0; r < 4; ++r) {
                if (sbase + r < nk)
                    out[(size_t)sl[sbase + r] * EE + e] = acc[r];
            }
        }
        if (c0 + 64 >= nk) break;        // common case: exactly one chunk
        __syncthreads();                 // MFMA readers done
        stage(c0 + 64);
        __syncthreads();                 // writers done
    }
}

extern "C" void kernel_launch(void* const* d_in, const int* in_sizes, int n_in,
                              void* d_out, int out_size, void* d_ws, size_t ws_size,
                              hipStream_t stream)
{
    const float* values   = (const float*)d_in[0];
    const float* means    = (const float*)d_in[1];
    const float* stds     = (const float*)d_in[2];
    const int*   head_idx = (const int*)d_in[3];
    const float* w1       = (const float*)d_in[4];
    const float* b1       = (const float*)d_in[5];
    const float* W_heads  = (const float*)d_in[6];
    const float* b_heads  = (const float*)d_in[7];
    float* out = (float*)d_out;

    fused_kernel<<<dim3(KK, 4), 256, 0, stream>>>(
        values, means, stds, head_idx, w1, b1, W_heads, b_heads, out);
}

// Round 9
// 15.061 us; speedup vs baseline: 1.8923x; 1.0070x over previous
//
#include <hip/hip_runtime.h>
#include <hip/hip_bf16.h>
#include <math.h>

// Problem constants (match reference: B=4096, H=256, E=256, K=100)
#define BB 4096
#define HH 256
#define EE 256
#define KK 100
#define SLMAX 2048   // bucket capacity (max realistic nk ~75 @ B/K=41)

typedef __bf16 bf16x8 __attribute__((ext_vector_type(8)));
typedef float  f32x4  __attribute__((ext_vector_type(4)));

// tanh-form GELU; 2/(e+1) via v_rcp_f32 (rel err ~1e-5, far below bf16 lsb).
__device__ __forceinline__ float gelu_fast(float x) {
    const float x3 = x * x * x;
    const float y2 = fmaf(0.044715f, x3, x) * 1.5957691216057308f;  // 2*sqrt(2/pi)*(..)
    const float e  = __expf(y2);
    const float t  = 1.0f - 2.0f * __builtin_amdgcn_rcpf(e + 1.0f);
    return 0.5f * x * (1.0f + t);
}

__device__ __forceinline__ float norm_clip(float v, float m, float sd) {
    float z = (v - m) / fmaxf(sd, 1e-8f);
    return fminf(5.0f, fmaxf(-5.0f, z));
}

// Single fused kernel. grid = (K, 4). Block (k, et) owns output columns
// [et*64, et*64+64); wave w owns e-substrip et*64+w*16..+16.
// Phase order (latency-cover + register-lifetime driven):
//   0: issue head_idx loads (16) then W loads (64) — deepest-latency first
//   A: deterministic ballot-compaction (covers W drain partially)
//   C: gelu-stage chunk 0 into swizzled LDS (covers the rest)
//   D: convert wf -> bf16 B-frags (vmcnt waits land here, fully covered)
//   E: MFMA tiles + masked stores; stage next chunk only if nk > 64 (rare)
__global__ __launch_bounds__(256, 3) void fused_kernel(
    const float* __restrict__ values, const float* __restrict__ means,
    const float* __restrict__ stds, const int* __restrict__ head_idx,
    const float* __restrict__ w1, const float* __restrict__ b1,
    const float* __restrict__ W_heads, const float* __restrict__ b_heads,
    float* __restrict__ out)
{
    const int k    = blockIdx.x;
    const int et   = blockIdx.y;
    const int tid  = threadIdx.x;
    const int wave = tid >> 6;
    const int lane = tid & 63;
    const int col16 = lane & 15;   // e within 16-strip / D column
    const int kch   = lane >> 4;   // k-chunk group (8 consecutive k each)
    const int e = et * 64 + wave * 16 + col16;   // this lane's output column

    __shared__ int sl[SLMAX];                     // 8 KB
    __shared__ __align__(16) int cnt_lds[64];     // [round i][wave w]
    __shared__ __align__(16) __bf16 hid[64 * HH]; // 32 KB, XOR-swizzled

    // ---- Phase 0a: issue head_idx loads (needed first, shallow) ----
    int h16[16];
#pragma unroll
    for (int i = 0; i < 16; ++i) h16[i] = head_idx[i * 256 + tid];

    // ---- Phase 0b: issue W loads (64-deep; drained in phase D) ----
    float wf[8][8];
    {
        const float* __restrict__ Wke = W_heads + (size_t)k * (HH * EE) + e;
#pragma unroll
        for (int kk = 0; kk < 8; ++kk)
#pragma unroll
            for (int j = 0; j < 8; ++j)
                wf[kk][j] = Wke[(size_t)(kk * 32 + kch * 8 + j) * EE];
    }
    const float bias = b_heads[k * EE + e];

    // ---- Phase A: deterministic ballot-compaction ----
    int nk;
    {
        unsigned long long msk[16];
#pragma unroll
        for (int i = 0; i < 16; ++i) {
            msk[i] = __ballot(h16[i] == k);
            if (lane == 0) cnt_lds[i * 4 + wave] = __popcll(msk[i]);
        }
        __syncthreads();
        int base[16];
        int run = 0;
#pragma unroll
        for (int i = 0; i < 16; ++i) {
            const int4 c4 = *reinterpret_cast<const int4*>(&cnt_lds[i * 4]);
            int b0 = run;
            if (wave > 0) b0 += c4.x;
            if (wave > 1) b0 += c4.y;
            if (wave > 2) b0 += c4.z;
            base[i] = b0;
            run += c4.x + c4.y + c4.z + c4.w;
        }
        nk = run;
        if (nk == 0) return;
#pragma unroll
        for (int i = 0; i < 16; ++i) {
            if (h16[i] == k) {
                const int pos = base[i] + __popcll(msk[i] & ((1ull << lane) - 1));
                if (pos < SLMAX) sl[pos] = i * 256 + tid;
            }
        }
        if (nk > SLMAX) nk = SLMAX;
        __syncthreads();
    }

    // hid staging mapping: thread (rsub, cch) writes row rr*16+rsub,
    // 16B chunks cch and cch+16 (elements h = chunk*8..+8).
    const int rsub = tid >> 4;
    const int cch  = tid & 15;
    const float4 w1a = *reinterpret_cast<const float4*>(w1 + cch * 8);
    const float4 w1b = *reinterpret_cast<const float4*>(w1 + cch * 8 + 4);
    const float4 w1c = *reinterpret_cast<const float4*>(w1 + cch * 8 + 128);
    const float4 w1d = *reinterpret_cast<const float4*>(w1 + cch * 8 + 132);
    const float4 b1a = *reinterpret_cast<const float4*>(b1 + cch * 8);
    const float4 b1b = *reinterpret_cast<const float4*>(b1 + cch * 8 + 4);
    const float4 b1c = *reinterpret_cast<const float4*>(b1 + cch * 8 + 128);
    const float4 b1d = *reinterpret_cast<const float4*>(b1 + cch * 8 + 132);

    char* const hidp = reinterpret_cast<char*>(hid);

    // Stage one 64-sample chunk of hidden into swizzled LDS (tail rows skipped;
    // stale LDS there is finite garbage, masked at the output store).
    auto stage = [&](int c0) {
#pragma unroll
        for (int rr = 0; rr < 4; ++rr) {
            if (c0 + rr * 16 >= nk) break;           // uniform
            const int s_loc = rr * 16 + rsub;
            const int gi = c0 + s_loc;
            if (gi < nk) {
                const int sid = sl[gi];
                const float z = norm_clip(values[sid], means[sid], stds[sid]);
                bf16x8 lo, hi;
                lo[0] = (__bf16)gelu_fast(fmaf(z, w1a.x, b1a.x));
                lo[1] = (__bf16)gelu_fast(fmaf(z, w1a.y, b1a.y));
                lo[2] = (__bf16)gelu_fast(fmaf(z, w1a.z, b1a.z));
                lo[3] = (__bf16)gelu_fast(fmaf(z, w1a.w, b1a.w));
                lo[4] = (__bf16)gelu_fast(fmaf(z, w1b.x, b1b.x));
                lo[5] = (__bf16)gelu_fast(fmaf(z, w1b.y, b1b.y));
                lo[6] = (__bf16)gelu_fast(fmaf(z, w1b.z, b1b.z));
                lo[7] = (__bf16)gelu_fast(fmaf(z, w1b.w, b1b.w));
                hi[0] = (__bf16)gelu_fast(fmaf(z, w1c.x, b1c.x));
                hi[1] = (__bf16)gelu_fast(fmaf(z, w1c.y, b1c.y));
                hi[2] = (__bf16)gelu_fast(fmaf(z, w1c.z, b1c.z));
                hi[3] = (__bf16)gelu_fast(fmaf(z, w1c.w, b1c.w));
                hi[4] = (__bf16)gelu_fast(fmaf(z, w1d.x, b1d.x));
                hi[5] = (__bf16)gelu_fast(fmaf(z, w1d.y, b1d.y));
                hi[6] = (__bf16)gelu_fast(fmaf(z, w1d.z, b1d.z));
                hi[7] = (__bf16)gelu_fast(fmaf(z, w1d.w, b1d.w));
                char* bp = hidp + s_loc * 512;
                *reinterpret_cast<bf16x8*>(bp + ((cch        ^ (s_loc & 7)) << 4)) = lo;
                *reinterpret_cast<bf16x8*>(bp + (((cch + 16) ^ (s_loc & 7)) << 4)) = hi;
            }
        }
    };

    // ---- Phase C: stage chunk 0 (covers remaining W-load latency) ----
    stage(0);

    // ---- Phase D: convert W to bf16 B-frags (waits land here) ----
    bf16x8 wb[8];
#pragma unroll
    for (int kk = 0; kk < 8; ++kk)
#pragma unroll
        for (int j = 0; j < 8; ++j)
            wb[kk][j] = (__bf16)wf[kk][j];

    __syncthreads();

    // ---- Phase E: MFMA per chunk; stage next chunk only if needed ----
    for (int c0 = 0;; c0 += 64) {
        const int ntt = min(4, (nk - c0 + 15) >> 4);
        for (int tt = 0; tt < ntt; ++tt) {
            const int row = tt * 16 + col16;
            const char* ap = hidp + row * 512;
            f32x4 acc = (f32x4){bias, bias, bias, bias};
#pragma unroll
            for (int kk = 0; kk < 8; ++kk) {
                const bf16x8 a = *reinterpret_cast<const bf16x8*>(
                    ap + (((kk * 4 + kch) ^ (row & 7)) << 4));
                acc = __builtin_amdgcn_mfma_f32_16x16x32_bf16(a, wb[kk], acc, 0, 0, 0);
            }
            // D layout: col = lane&15 (e), row = kch*4 + r (sample slot)
            const int sbase = c0 + tt * 16 + kch * 4;
#pragma unroll
            for (int r = 0; r < 4; ++r) {
                if (sbase + r < nk)
                    out[(size_t)sl[sbase + r] * EE + e] = acc[r];
            }
        }
        if (c0 + 64 >= nk) break;        // common case: exactly one chunk
        __syncthreads();                 // MFMA readers done
        stage(c0 + 64);
        __syncthreads();                 // writers done
    }
}

extern "C" void kernel_launch(void* const* d_in, const int* in_sizes, int n_in,
                              void* d_out, int out_size, void* d_ws, size_t ws_size,
                              hipStream_t stream)
{
    const float* values   = (const float*)d_in[0];
    const float* means    = (const float*)d_in[1];
    const float* stds     = (const float*)d_in[2];
    const int*   head_idx = (const int*)d_in[3];
    const float* w1       = (const float*)d_in[4];
    const float* b1       = (const float*)d_in[5];
    const float* W_heads  = (const float*)d_in[6];
    const float* b_heads  = (const float*)d_in[7];
    float* out = (float*)d_out;

    fused_kernel<<<dim3(KK, 4), 256, 0, stream>>>(
        values, means, stds, head_idx, w1, b1, W_heads, b_heads, out);
}